// Round 5
// baseline (241.996 us; speedup 1.0000x reference)
//
#include <hip/hip_runtime.h>
#include <stdint.h>

// ---------------------------------------------------------------------------
// MAB block: O = LN2(O1 + relu(O1@Wo+bo)), O1 = LN1(Q + MHA(Q,K,V,mask))
// ---------------------------------------------------------------------------

typedef unsigned short u16;
typedef unsigned int u32;
typedef __attribute__((ext_vector_type(8))) short s16x8;   // bf16x8 frag (4 VGPR)
typedef __attribute__((ext_vector_type(4))) float f32x4;
typedef __attribute__((ext_vector_type(16))) float f32x16; // 32x32 MFMA C/D
typedef __attribute__((ext_vector_type(4))) u16 u16x4;

typedef __attribute__((address_space(1))) const void* as1cv;
typedef __attribute__((address_space(3))) void* as3v;

#define DEVINL __device__ __forceinline__

DEVINL u16 f2bf(float f) {
  union { float f; u32 u; } v; v.f = f;
  return (u16)((v.u + 0x7FFFu + ((v.u >> 16) & 1u)) >> 16);  // RNE
}
DEVINL float bf2f(u16 x) {
  union { u32 u; float f; } v; v.u = ((u32)x) << 16;
  return v.f;
}
DEVINL u32 cvtpk_bf16(float lo, float hi) {  // packed RNE f32x2 -> bf16x2
  u32 r;
  asm("v_cvt_pk_bf16_f32 %0, %1, %2" : "=v"(r) : "v"(lo), "v"(hi));
  return r;
}
DEVINL float fexp2(float x) {  // raw v_exp_f32 (2^x)
  float r;
  asm("v_exp_f32 %0, %1" : "=v"(r) : "v"(x));
  return r;
}
DEVINL void gload_lds16(const void* g, void* l) {
  __builtin_amdgcn_global_load_lds((as1cv)g, (as3v)l, 16, 0, 0);
}
DEVINL f32x4 mfma16(s16x8 a, s16x8 b, f32x4 c) {
  return __builtin_amdgcn_mfma_f32_16x16x32_bf16(a, b, c, 0, 0, 0);
}
DEVINL f32x16 mfma32(s16x8 a, s16x8 b, f32x16 c) {
  return __builtin_amdgcn_mfma_f32_32x32x16_bf16(a, b, c, 0, 0, 0);
}

// ---------------------------------------------------------------------------
// mask prep: detect layout (bool/int/float), write pre-folded softmax bias:
// unmasked -> -8*log2e, masked -> -3e30  (p = exp2(s*scale*log2e + bias))
// ---------------------------------------------------------------------------
__global__ void prep_mask(const u32* __restrict__ mraw, float* __restrict__ maskb) {
  __shared__ int mode;
  int t = threadIdx.x;
  int fB = 0, fF = 0;
  for (int i = t; i < 2048; i += 256) {
    u32 v = mraw[i];
    if (v == 0x3F800000u) fF = 1;
    else if (v > 1u) fB = 1;
  }
  if (t == 0) mode = 0;
  __syncthreads();
  if (fB) atomicOr(&mode, 1);
  if (fF) atomicOr(&mode, 2);
  __syncthreads();
  int md = mode;
  int idx = blockIdx.x * 256 + t;
  int v;
  if (md & 1)       v = ((const unsigned char*)mraw)[idx] != 0;
  else if (md & 2)  v = ((const float*)mraw)[idx] != 0.0f;
  else              v = ((const int*)mraw)[idx] != 0;
  maskb[idx] = v ? -3e30f : -11.54156032f;
}

// f32 -> bf16 for X and Y in one launch
__global__ void cvt_f2bf2(const float* __restrict__ in0, u16* __restrict__ out0,
                          const float* __restrict__ in1, u16* __restrict__ out1,
                          int n4) {
  int i = blockIdx.x * blockDim.x + threadIdx.x;
  const float* in = in0;
  u16* out = out0;
  if (i >= n4) { i -= n4; in = in1; out = out1; }
  float4 v = *(const float4*)(in + (size_t)i * 4);
  u16x4 o; o[0] = f2bf(v.x); o[1] = f2bf(v.y); o[2] = f2bf(v.z); o[3] = f2bf(v.w);
  *(u16x4*)(out + (size_t)i * 4) = o;
}

__global__ void transpose_cvt(const float* __restrict__ W0, const float* __restrict__ W1,
                              const float* __restrict__ W2, const float* __restrict__ W3,
                              u16* __restrict__ T0, u16* __restrict__ T1,
                              u16* __restrict__ T2, u16* __restrict__ T3) {
  const float* W = (blockIdx.z == 0) ? W0 : (blockIdx.z == 1) ? W1 : (blockIdx.z == 2) ? W2 : W3;
  u16* T = (blockIdx.z == 0) ? T0 : (blockIdx.z == 1) ? T1 : (blockIdx.z == 2) ? T2 : T3;
  __shared__ float tile[32][33];
  int tx = threadIdx.x, ty = threadIdx.y;
  int N0 = blockIdx.x << 5, K0 = blockIdx.y << 5;
#pragma unroll
  for (int i = 0; i < 4; ++i)
    tile[ty + i * 8][tx] = W[(size_t)(K0 + ty + i * 8) * 1024 + N0 + tx];
  __syncthreads();
#pragma unroll
  for (int i = 0; i < 4; ++i)
    T[(size_t)(N0 + ty + i * 8) * 1024 + K0 + tx] = f2bf(tile[tx][ty + i * 8]);
}

// ---------------------------------------------------------------------------
// NT GEMM: 128x128 tile, BK=64, 4 waves, mfma 16x16x32 bf16.
// MODE 1: outBF = bf16(acc+bias)
// MODE 2: outBF transposed Vt[(b*1024+n)][m%1024]
// MODE 3: outBF = bf16(bf2f(residBF) + relu(acc+bias))
// ---------------------------------------------------------------------------
template <int MODE>
__global__ __launch_bounds__(256, 2) void gemm_nt(
    const u16* __restrict__ A, const u16* __restrict__ Bt,
    const float* __restrict__ bias, float* __restrict__ outF,
    u16* __restrict__ outBF, const u16* __restrict__ residBF) {
  __shared__ u16 lA[128 * 64];
  __shared__ u16 lB[128 * 64];

  const int id = blockIdx.x;
  const int cpx = gridDim.x >> 3;
  const int swz = (id & 7) * cpx + (id >> 3);
  const int mb = swz >> 3;
  const int nb = swz & 7;

  const int tid = threadIdx.x;
  const int w = tid >> 6, l = tid & 63;
  const int wm = w >> 1, wn = w & 1;
  const int lrow = l & 15, lk = l >> 4;

  const int sr = l >> 3;
  const int scol = ((l & 7) << 4) ^ (sr << 4);
  const char* gA = (const char*)A + (size_t)(mb * 128) * 2048;
  const char* gB = (const char*)Bt + (size_t)(nb * 128) * 2048;

  f32x4 acc[4][4];
#pragma unroll
  for (int i = 0; i < 4; ++i)
#pragma unroll
    for (int j = 0; j < 4; ++j) acc[i][j] = f32x4{0.f, 0.f, 0.f, 0.f};

  for (int kt = 0; kt < 16; ++kt) {
    const int kb = kt * 128;
#pragma unroll
    for (int c = 0; c < 4; ++c) {
      int row = (w * 4 + c) * 8 + sr;
      gload_lds16(gA + (size_t)row * 2048 + kb + scol, (char*)lA + (w * 4 + c) * 1024);
      gload_lds16(gB + (size_t)row * 2048 + kb + scol, (char*)lB + (w * 4 + c) * 1024);
    }
    __syncthreads();
#pragma unroll
    for (int kc = 0; kc < 2; ++kc) {
      s16x8 af[4], bfr[4];
#pragma unroll
      for (int mi = 0; mi < 4; ++mi) {
        int row = wm * 64 + mi * 16 + lrow;
        int off = row * 128 + ((lk * 16 + kc * 64) ^ ((row & 7) << 4));
        af[mi] = *(const s16x8*)((const char*)lA + off);
      }
#pragma unroll
      for (int ni = 0; ni < 4; ++ni) {
        int row = wn * 64 + ni * 16 + lrow;
        int off = row * 128 + ((lk * 16 + kc * 64) ^ ((row & 7) << 4));
        bfr[ni] = *(const s16x8*)((const char*)lB + off);
      }
      __builtin_amdgcn_s_setprio(1);
#pragma unroll
      for (int mi = 0; mi < 4; ++mi)
#pragma unroll
        for (int ni = 0; ni < 4; ++ni)
          acc[mi][ni] = mfma16(af[mi], bfr[ni], acc[mi][ni]);
      __builtin_amdgcn_s_setprio(0);
    }
    __syncthreads();
  }

  const int growb = mb * 128 + wm * 64;
  const int gcolb = nb * 128 + wn * 64;
  float bs[4];
#pragma unroll
  for (int ni = 0; ni < 4; ++ni) bs[ni] = bias[gcolb + ni * 16 + lrow];

#pragma unroll
  for (int mi = 0; mi < 4; ++mi) {
    const int grow0 = growb + mi * 16 + lk * 4;
#pragma unroll
    for (int ni = 0; ni < 4; ++ni) {
      const int gcol = gcolb + ni * 16 + lrow;
      if (MODE == 2) {
        u16x4 pk;
#pragma unroll
        for (int r = 0; r < 4; ++r) pk[r] = f2bf(acc[mi][ni][r] + bs[ni]);
        size_t flat = ((size_t)((grow0 >> 10) << 10) + gcol) * 1024 + (grow0 & 1023);
        *(u16x4*)(outBF + flat) = pk;
      } else {
#pragma unroll
        for (int r = 0; r < 4; ++r) {
          float v = acc[mi][ni][r] + bs[ni];
          size_t idx = (size_t)(grow0 + r) * 1024 + gcol;
          if (MODE == 1) { outBF[idx] = f2bf(v); }
          if (MODE == 3) { outBF[idx] = f2bf(bf2f(residBF[idx]) + fmaxf(v, 0.f)); }
        }
      }
    }
  }
}

// ---------------------------------------------------------------------------
// flash attention v5: 2-way SPLIT-KV (static-max softmax is exactly additive:
// U = U0+U1, l = l0+l1). grid 1024, KVBLK=64 single-buffered, LDS 34KB ->
// 4 blocks/CU = 16 waves/CU (2x TLP of v4; drains hidden by other blocks).
// Swapped QK^T on 32x32x16 MFMA, permlane32_swap PV exchange, bf16 U out.
// ---------------------------------------------------------------------------
__global__ __launch_bounds__(256, 4) void attn_fwd(
    const u16* __restrict__ Qbf, const u16* __restrict__ Kbf,
    const u16* __restrict__ Vt, const float* __restrict__ maskb,
    u16* __restrict__ U, float* __restrict__ lsum) {
  __shared__ u16 lK[64 * 128];    // 16KB [key][d] rows 256B, swz (key&15)<<4
  __shared__ u16 lV[128 * 64];    // 16KB [d][key] rows 128B, swz (d&7)<<4
  __shared__ float lM[512];       // 2KB pre-folded softmax bias (this half)

  const int id = blockIdx.x;
  const int xcd = id & 7, seq = id >> 3;        // 128 blocks per XCD
  const int bh = xcd * 8 + (seq >> 4);          // 8 bh per XCD (K/V L2 locality)
  const int sub = seq & 15;
  const int qb = sub >> 1, half = sub & 1;
  const int b = bh >> 3, h = bh & 7;
  const int tid = threadIdx.x;
  const int w = tid >> 6, l = tid & 63;
  const int q32 = l & 31, hi = l >> 5;

  // Q fragments: B-operand, lane&31 = q-row
  const u16* Qrow = Qbf + ((size_t)(b * 1024 + qb * 128 + w * 32 + q32)) * 1024 + h * 128;
  s16x8 qf[8];
#pragma unroll
  for (int dc = 0; dc < 8; ++dc) qf[dc] = *(const s16x8*)(Qrow + dc * 16 + hi * 8);

  // staging source lane offsets (pre-swizzled; LDS dst is linear)
  const int srK = l >> 4, slK = l & 15;
  const int srV = l >> 3, slV = l & 7;
  int soK[4], soV[4];
#pragma unroll
  for (int c = 0; c < 4; ++c) {
    int rowK = (w * 4 + c) * 4 + srK;
    soK[c] = rowK * 2048 + ((slK << 4) ^ ((rowK & 15) << 4));
    int dV = (w * 4 + c) * 8 + srV;
    soV[c] = dV * 2048 + ((slV << 4) ^ ((dV & 7) << 4));
  }
  const char* pgK = (const char*)(Kbf + ((size_t)(b * 1024)) * 1024 + h * 128);
  const char* pgV = (const char*)(Vt + ((size_t)(b * 1024 + h * 128)) * 1024);

  // ds_read lane offsets (loop-invariant)
  int loK[8], loV[4];
#pragma unroll
  for (int c = 0; c < 8; ++c)
    loK[c] = q32 * 256 + ((c * 32 + hi * 16) ^ ((q32 & 15) << 4));
#pragma unroll
  for (int c = 0; c < 4; ++c)
    loV[c] = q32 * 128 + ((c * 32 + hi * 16) ^ ((q32 & 7) << 4));

  // stage this half's mask bias (512 floats); first __syncthreads covers it
  if (w == 0) {
#pragma unroll
    for (int c = 0; c < 2; ++c)
      gload_lds16(maskb + b * 1024 + half * 512 + c * 256 + l * 4, (char*)lM + c * 1024);
  }

  float l_ = 0.f;
  f32x16 oacc[4];
#pragma unroll
  for (int i = 0; i < 4; ++i)
#pragma unroll
    for (int r = 0; r < 16; ++r) oacc[i][r] = 0.f;

  const float SCL = 0.04508422f;  // (1/32) * log2(e)
  const char* pM0 = (const char*)lM + hi * 16;
  const int tbase = half * 8;

  for (int t8 = 0; t8 < 8; ++t8) {
    const int t = tbase + t8;
    // ---- stage K (64 key-rows x 256B) + V (128 d-rows x 128B)
    {
      const char* pk_ = pgK + (size_t)t * 131072;
      const char* pv_ = pgV + (size_t)t * 128;
#pragma unroll
      for (int c = 0; c < 4; ++c) {
        gload_lds16(pk_ + soK[c], (char*)lK + w * 4096 + c * 1024);
        gload_lds16(pv_ + soV[c], (char*)lV + w * 4096 + c * 1024);
      }
    }
    __syncthreads();  // vmcnt(0) drain + barrier: tile visible to all waves

    // ---- S^T = K Q^T
    f32x16 sc[2];
#pragma unroll
    for (int kb = 0; kb < 2; ++kb)
#pragma unroll
      for (int r = 0; r < 16; ++r) sc[kb][r] = 0.f;
    __builtin_amdgcn_s_setprio(1);
#pragma unroll
    for (int dc = 0; dc < 8; ++dc) {
#pragma unroll
      for (int kb = 0; kb < 2; ++kb) {
        s16x8 kf = *(const s16x8*)((const char*)lK + loK[dc] + kb * 8192);
        sc[kb] = mfma32(kf, qf[dc], sc[kb]);
      }
    }
    __builtin_amdgcn_s_setprio(0);

    // ---- p = exp2(s*SCL + bias), row-sum
    const char* pMa = pM0 + t8 * 256;
    float rs = 0.f;
#pragma unroll
    for (int kb = 0; kb < 2; ++kb) {
      f32x4 mv[4];
#pragma unroll
      for (int g = 0; g < 4; ++g)
        mv[g] = *(const f32x4*)(pMa + kb * 128 + g * 32);
#pragma unroll
      for (int r = 0; r < 16; ++r) {
        float pe = fexp2(fmaf(sc[kb][r], SCL, mv[r >> 2][r & 3]));
        sc[kb][r] = pe;
        rs += pe;
      }
    }
    rs += __shfl_xor(rs, 32);
    l_ += rs;

    // ---- pack p to bf16 pairs
    u32 pk[2][8];
#pragma unroll
    for (int kb = 0; kb < 2; ++kb)
#pragma unroll
      for (int r2 = 0; r2 < 8; ++r2)
        pk[kb][r2] = cvtpk_bf16(sc[kb][2 * r2], sc[kb][2 * r2 + 1]);

    // ---- PV
#pragma unroll
    for (int kc = 0; kc < 4; ++kc) {
      const int kb = kc >> 1;
      const int ra = (kc & 1) * 4;
      u32 x0 = pk[kb][ra + 0], y0 = pk[kb][ra + 2];
      u32 x1 = pk[kb][ra + 1], y1 = pk[kb][ra + 3];
      asm("v_permlane32_swap_b32 %0, %1" : "+v"(x0), "+v"(y0));
      asm("v_permlane32_swap_b32 %0, %1" : "+v"(x1), "+v"(y1));
      union { u32 u[4]; s16x8 v; } pa;
      pa.u[0] = x0; pa.u[1] = x1; pa.u[2] = y0; pa.u[3] = y1;
      __builtin_amdgcn_s_setprio(1);
#pragma unroll
      for (int nb = 0; nb < 4; ++nb) {
        s16x8 vb = *(const s16x8*)((const char*)lV + loV[kc] + nb * 4096);
        oacc[nb] = mfma32(pa.v, vb, oacc[nb]);
      }
      __builtin_amdgcn_s_setprio(0);
    }
    __syncthreads();  // all reads done before next tile's stage
  }

  // ---- write unnormalized U (bf16) + row-sums (f32); combine happens in LN1
  if (hi == 0)
    lsum[half * 65536 + bh * 1024 + qb * 128 + w * 32 + q32] = l_;
  u16* ubase = U + (size_t)half * 8388608 +
               ((size_t)(b * 1024 + qb * 128 + w * 32)) * 1024 + h * 128;
#pragma unroll
  for (int r = 0; r < 16; ++r) {
    int qr = (r & 3) + 8 * (r >> 2) + 4 * hi;
#pragma unroll
    for (int nb = 0; nb < 4; ++nb)
      ubase[(size_t)qr * 1024 + nb * 32 + q32] = f2bf(oacc[nb][r]);
  }
}

// ---------------------------------------------------------------------------
// LN1 + split-KV combine: attn = (U0+U1) / (l0+l1); h = Q + attn; out = LN(h)
// ---------------------------------------------------------------------------
__global__ __launch_bounds__(256) void ln1_combine(
    const u16* __restrict__ Qbf, const u16* __restrict__ U,
    const float* __restrict__ lsum, const float* __restrict__ g,
    const float* __restrict__ bt, u16* __restrict__ outBF) {
  const int row = blockIdx.x;
  const int c = threadIdx.x << 2;
  const size_t base = (size_t)row * 1024 + c;
  const int b = row >> 10, qx = row & 1023;
  const int hh = c >> 7;
  const int li = (b * 8 + hh) * 1024 + qx;
  const float lt = lsum[li] + lsum[65536 + li];
  const float inv = (lt > 1e-20f) ? (1.0f / lt) : 0.f;  // fully-masked row -> 0
  u16x4 uq = *(const u16x4*)(Qbf + base);
  u16x4 u0 = *(const u16x4*)(U + base);
  u16x4 u1 = *(const u16x4*)(U + 8388608 + base);
  float4 h;
  h.x = bf2f(uq[0]) + (bf2f(u0[0]) + bf2f(u1[0])) * inv;
  h.y = bf2f(uq[1]) + (bf2f(u0[1]) + bf2f(u1[1])) * inv;
  h.z = bf2f(uq[2]) + (bf2f(u0[2]) + bf2f(u1[2])) * inv;
  h.w = bf2f(uq[3]) + (bf2f(u0[3]) + bf2f(u1[3])) * inv;
  float s = (h.x + h.y) + (h.z + h.w);
  float q = (h.x * h.x + h.y * h.y) + (h.z * h.z + h.w * h.w);
#pragma unroll
  for (int msk = 1; msk < 64; msk <<= 1) {
    s += __shfl_xor(s, msk);
    q += __shfl_xor(q, msk);
  }
  __shared__ float sh[8];
  const int w = threadIdx.x >> 6;
  if ((threadIdx.x & 63) == 0) { sh[w] = s; sh[4 + w] = q; }
  __syncthreads();
  s = (sh[0] + sh[1]) + (sh[2] + sh[3]);
  q = (sh[4] + sh[5]) + (sh[6] + sh[7]);
  const float mu = s * (1.f / 1024.f);
  const float var = q * (1.f / 1024.f) - mu * mu;
  const float rstd = rsqrtf(var + 1e-5f);
  const float4 gv = *(const float4*)(g + c);
  const float4 bv = *(const float4*)(bt + c);
  u16x4 ub;
  ub[0] = f2bf((h.x - mu) * rstd * gv.x + bv.x);
  ub[1] = f2bf((h.y - mu) * rstd * gv.y + bv.y);
  ub[2] = f2bf((h.z - mu) * rstd * gv.z + bv.z);
  ub[3] = f2bf((h.w - mu) * rstd * gv.w + bv.w);
  *(u16x4*)(outBF + base) = ub;
}

// ---------------------------------------------------------------------------
// fused residual + LayerNorm over 1024 cols (LN2 path).
// ---------------------------------------------------------------------------
__global__ __launch_bounds__(256) void ln_fused(
    const float* __restrict__ aF, const u16* __restrict__ aBF,
    const u16* __restrict__ baddBF, const float* __restrict__ g,
    const float* __restrict__ bt, float* __restrict__ outF,
    u16* __restrict__ outBF) {
  const int row = blockIdx.x;
  const int c = threadIdx.x << 2;
  const size_t base = (size_t)row * 1024 + c;
  float4 h;
  if (aF) {
    h = *(const float4*)(aF + base);
  } else {
    u16x4 u = *(const u16x4*)(aBF + base);
    h.x = bf2f(u[0]); h.y = bf2f(u[1]); h.z = bf2f(u[2]); h.w = bf2f(u[3]);
  }
  if (baddBF) {
    u16x4 u = *(const u16x4*)(baddBF + base);
    h.x += bf2f(u[0]); h.y += bf2f(u[1]); h.z += bf2f(u[2]); h.w += bf2f(u[3]);
  }
  float s = (h.x + h.y) + (h.z + h.w);
  float q = (h.x * h.x + h.y * h.y) + (h.z * h.z + h.w * h.w);
#pragma unroll
  for (int msk = 1; msk < 64; msk <<= 1) {
    s += __shfl_xor(s, msk);
    q += __shfl_xor(q, msk);
  }
  __shared__ float sh[8];
  const int w = threadIdx.x >> 6;
  if ((threadIdx.x & 63) == 0) { sh[w] = s; sh[4 + w] = q; }
  __syncthreads();
  s = (sh[0] + sh[1]) + (sh[2] + sh[3]);
  q = (sh[4] + sh[5]) + (sh[6] + sh[7]);
  const float mu = s * (1.f / 1024.f);
  const float var = q * (1.f / 1024.f) - mu * mu;
  const float rstd = rsqrtf(var + 1e-5f);
  const float4 gv = *(const float4*)(g + c);
  const float4 bv = *(const float4*)(bt + c);
  float4 o;
  o.x = (h.x - mu) * rstd * gv.x + bv.x;
  o.y = (h.y - mu) * rstd * gv.y + bv.y;
  o.z = (h.z - mu) * rstd * gv.z + bv.z;
  o.w = (h.w - mu) * rstd * gv.w + bv.w;
  if (outF) *(float4*)(outF + base) = o;
  if (outBF) {
    u16x4 ub; ub[0] = f2bf(o.x); ub[1] = f2bf(o.y); ub[2] = f2bf(o.z); ub[3] = f2bf(o.w);
    *(u16x4*)(outBF + base) = ub;
  }
}

// ---------------------------------------------------------------------------
extern "C" void kernel_launch(void* const* d_in, const int* in_sizes, int n_in,
                              void* d_out, int out_size, void* d_ws, size_t ws_size,
                              hipStream_t stream) {
  const float* X  = (const float*)d_in[0];
  const float* Y  = (const float*)d_in[1];
  const void*  mask = d_in[2];
  const float* Wq = (const float*)d_in[3];
  const float* bq = (const float*)d_in[4];
  const float* Wk = (const float*)d_in[5];
  const float* bk = (const float*)d_in[6];
  const float* Wv = (const float*)d_in[7];
  const float* bv = (const float*)d_in[8];
  const float* Wo = (const float*)d_in[9];
  const float* bo = (const float*)d_in[10];
  const float* g1 = (const float*)d_in[11];
  const float* b1 = (const float*)d_in[12];
  const float* g2 = (const float*)d_in[13];
  const float* b2 = (const float*)d_in[14];
  float* out = (float*)d_out;

  char* ws = (char*)d_ws;
  const size_t MB = 1024ull * 1024ull;
  u16* Xbf    = (u16*)(ws + 0);         // 16MB, dead after Q-gemm -> O1bf
  u16* Ybf    = (u16*)(ws + 16 * MB);   // 16MB, dead after V-gemm -> lsum
  u16* Qbf    = (u16*)(ws + 32 * MB);   // 16MB (alive through LN1)
  u16* Kbf    = (u16*)(ws + 48 * MB);   // 16MB, dead after attn -> Rbf
  u16* Vt     = (u16*)(ws + 64 * MB);   // 16MB
  u16* Ubf    = (u16*)(ws + 80 * MB);   // 32MB (split-KV partials), dead after LN1
  u16* Wqt = (u16*)(ws + 112 * MB);
  u16* Wkt = (u16*)(ws + 114 * MB);
  u16* Wvt = (u16*)(ws + 116 * MB);
  u16* Wot = (u16*)(ws + 118 * MB);
  float* maskb = (float*)(ws + 120 * MB);  // 32KB
  float* lsum  = (float*)(ws + 16 * MB);   // 512KB (Ybf reuse, written by attn)
  u16* Rbf = Kbf;
  u16* O1bf = Xbf;

  prep_mask<<<dim3(32), dim3(256), 0, stream>>>((const u32*)mask, maskb);
  cvt_f2bf2<<<dim3(16384), dim3(256), 0, stream>>>(X, Xbf, Y, Ybf, 2097152);
  transpose_cvt<<<dim3(32, 32, 4), dim3(32, 8), 0, stream>>>(Wq, Wk, Wv, Wo, Wqt, Wkt, Wvt, Wot);

  gemm_nt<1><<<dim3(512), dim3(256), 0, stream>>>(Xbf, Wqt, bq, nullptr, Qbf, nullptr);
  gemm_nt<1><<<dim3(512), dim3(256), 0, stream>>>(Ybf, Wkt, bk, nullptr, Kbf, nullptr);
  gemm_nt<2><<<dim3(512), dim3(256), 0, stream>>>(Ybf, Wvt, bv, nullptr, Vt, nullptr);

  attn_fwd<<<dim3(1024), dim3(256), 0, stream>>>(Qbf, Kbf, Vt, maskb, Ubf, lsum);

  ln1_combine<<<dim3(8192), dim3(256), 0, stream>>>(Qbf, Ubf, lsum, g1, b1, O1bf);
  gemm_nt<3><<<dim3(512), dim3(256), 0, stream>>>(O1bf, Wot, bo, nullptr, Rbf, O1bf);
  ln_fused<<<dim3(8192), dim3(256), 0, stream>>>(nullptr, Rbf, nullptr, g2, b2, out, nullptr);
}